// Round 1
// baseline (12559.921 us; speedup 1.0000x reference)
//
#include <hip/hip_runtime.h>

#define N_ITER 20
#define ALPHA 0.01f

__device__ __forceinline__ float csign(int a, int b) {
    int s = 0;
    for (int aa = a >> 1; aa; aa >>= 1) s += __popc(aa & b);
    return (s & 1) ? -1.0f : 1.0f;
}

__device__ __forceinline__ float revsign(int b) {
    int k = __popc(b);
    return ((k * (k - 1) / 2) & 1) ? -1.0f : 1.0f;
}

// Build flattened GP matrices from W [P, Q, 8]:
//   forward  Mf[(q*8+a), (p*8+c)] = sign(a, a^c) * W[p,q,a^c]            (dims [Q*8, P*8])
//   reverse  Mr[(p*8+a), (q*8+c)] = sign(a, a^c) * REV[a^c] * W[p,q,a^c] (dims [P*8, Q*8])
__global__ void build_M_kernel(const float* __restrict__ W, float* __restrict__ Mf,
                               float* __restrict__ Mr, int P, int Q) {
    int idx = blockIdx.x * blockDim.x + threadIdx.x;
    int total = P * Q * 64;
    if (idx >= total) return;
    int c = idx & 7;
    int a = (idx >> 3) & 7;
    int pq = idx >> 6;
    int q = pq % Q;
    int p = pq / Q;
    int b = a ^ c;
    float w = W[((size_t)p * Q + q) * 8 + b];
    float s = csign(a, b);
    Mf[(size_t)(q * 8 + a) * (P * 8) + (p * 8 + c)] = s * w;
    Mr[(size_t)(p * 8 + a) * (Q * 8) + (q * 8 + c)] = s * revsign(b) * w;
}

// Tiled fp32 GEMM, 64x64 tile, BK=16, 256 threads, 4x4 per thread.
// MODE 0: C = A@B
// MODE 1: C = X1 - A@B
// MODE 2: T = A@B; g = clip(-T + X1 - X2); H = X1 - ALPHA*g   (X1 == H)
// MODE 3: T = A@B; g = clip(-T);           H = X1 - ALPHA*g   (X1 == H)
template <int MODE>
__global__ __launch_bounds__(256) void gemm_ep(const float* __restrict__ A,
                                               const float* __restrict__ Bm,
                                               float* __restrict__ C,
                                               const float* __restrict__ X1,
                                               const float* __restrict__ X2,
                                               float* __restrict__ H,
                                               int M, int N, int K) {
    __shared__ float As[16][64];
    __shared__ float Bs[16][64];
    const int t = threadIdx.x;
    const int tx = t & 15;
    const int ty = t >> 4;
    const int row0 = blockIdx.y * 64;
    const int col0 = blockIdx.x * 64;

    float acc[4][4];
#pragma unroll
    for (int i = 0; i < 4; ++i)
#pragma unroll
        for (int j = 0; j < 4; ++j) acc[i][j] = 0.0f;

    const int ar = t >> 2;         // 0..63 row within A tile
    const int ak = (t & 3) << 2;   // 0,4,8,12 k within tile
    const int bk = t >> 4;         // 0..15 k within B tile
    const int bn = (t & 15) << 2;  // 0..60 col within tile

    for (int k0 = 0; k0 < K; k0 += 16) {
        float4 av = *(const float4*)(A + (size_t)(row0 + ar) * K + (k0 + ak));
        As[ak + 0][ar] = av.x;
        As[ak + 1][ar] = av.y;
        As[ak + 2][ar] = av.z;
        As[ak + 3][ar] = av.w;
        *(float4*)&Bs[bk][bn] = *(const float4*)(Bm + (size_t)(k0 + bk) * N + (col0 + bn));
        __syncthreads();
#pragma unroll
        for (int kk = 0; kk < 16; ++kk) {
            float4 a4 = *(const float4*)&As[kk][ty * 4];
            float4 b4 = *(const float4*)&Bs[kk][tx * 4];
            float aa[4] = {a4.x, a4.y, a4.z, a4.w};
            float bb[4] = {b4.x, b4.y, b4.z, b4.w};
#pragma unroll
            for (int i = 0; i < 4; ++i)
#pragma unroll
                for (int j = 0; j < 4; ++j) acc[i][j] = fmaf(aa[i], bb[j], acc[i][j]);
        }
        __syncthreads();
    }

#pragma unroll
    for (int i = 0; i < 4; ++i) {
        int r = row0 + ty * 4 + i;
        size_t off = (size_t)r * N + (col0 + tx * 4);
        if (MODE == 0) {
            float4 o = {acc[i][0], acc[i][1], acc[i][2], acc[i][3]};
            *(float4*)(C + off) = o;
        } else if (MODE == 1) {
            float4 x = *(const float4*)(X1 + off);
            float4 o = {x.x - acc[i][0], x.y - acc[i][1], x.z - acc[i][2], x.w - acc[i][3]};
            *(float4*)(C + off) = o;
        } else if (MODE == 2) {
            float4 h = *(const float4*)(X1 + off);
            float4 p = *(const float4*)(X2 + off);
            float g0 = fminf(fmaxf(-acc[i][0] + h.x - p.x, -1.0f), 1.0f);
            float g1 = fminf(fmaxf(-acc[i][1] + h.y - p.y, -1.0f), 1.0f);
            float g2 = fminf(fmaxf(-acc[i][2] + h.z - p.z, -1.0f), 1.0f);
            float g3 = fminf(fmaxf(-acc[i][3] + h.w - p.w, -1.0f), 1.0f);
            float4 o = {h.x - ALPHA * g0, h.y - ALPHA * g1, h.z - ALPHA * g2, h.w - ALPHA * g3};
            *(float4*)(H + off) = o;
        } else {  // MODE 3
            float4 h = *(const float4*)(X1 + off);
            float g0 = fminf(fmaxf(-acc[i][0], -1.0f), 1.0f);
            float g1 = fminf(fmaxf(-acc[i][1], -1.0f), 1.0f);
            float g2 = fminf(fmaxf(-acc[i][2], -1.0f), 1.0f);
            float g3 = fminf(fmaxf(-acc[i][3], -1.0f), 1.0f);
            float4 o = {h.x - ALPHA * g0, h.y - ALPHA * g1, h.z - ALPHA * g2, h.w - ALPHA * g3};
            *(float4*)(H + off) = o;
        }
    }
}

__global__ void sub_kernel(const float* __restrict__ A, const float* __restrict__ Bv,
                           float* __restrict__ C, int n4) {
    int i = blockIdx.x * blockDim.x + threadIdx.x;
    if (i < n4) {
        float4 a = ((const float4*)A)[i];
        float4 b = ((const float4*)Bv)[i];
        float4 o = {a.x - b.x, a.y - b.y, a.z - b.z, a.w - b.w};
        ((float4*)C)[i] = o;
    }
}

extern "C" void kernel_launch(void* const* d_in, const int* in_sizes, int n_in,
                              void* d_out, int out_size, void* d_ws, size_t ws_size,
                              hipStream_t stream) {
    const float* X  = (const float*)d_in[0];  // [4096, 256, 8]
    const float* W1 = (const float*)d_in[1];  // [256, 128, 8]
    const float* W2 = (const float*)d_in[2];  // [128, 64, 8]
    const float* h1 = (const float*)d_in[3];  // [4096, 128, 8]
    const float* h2 = (const float*)d_in[4];  // [4096, 64, 8]
    float* out = (float*)d_out;

    const int B = 4096;
    const size_t szX  = (size_t)B * 256 * 8;  // 8388608
    const size_t szH1 = (size_t)B * 128 * 8;  // 4194304
    const size_t szH2 = (size_t)B * 64 * 8;   // 2097152

    float* outX = out;
    float* H1 = out + szX;
    float* H2 = H1 + szH1;
    float* E  = outX;  // scratch: E1 [4096,2048] / E2 [4096,1024]; x copied in at the end

    float* ws  = (float*)d_ws;
    float* M1  = ws;                        // [1024, 2048]
    float* M1r = M1 + (size_t)1024 * 2048;  // [2048, 1024]
    float* M2  = M1r + (size_t)2048 * 1024; // [512, 1024]
    float* M2r = M2 + (size_t)512 * 1024;   // [1024, 512]
    float* P2  = M2r + (size_t)1024 * 512;  // [4096, 1024]

    build_M_kernel<<<(256 * 128 * 64 + 255) / 256, 256, 0, stream>>>(W1, M1, M1r, 256, 128);
    build_M_kernel<<<(128 * 64 * 64 + 255) / 256, 256, 0, stream>>>(W2, M2, M2r, 128, 64);

    hipMemcpyAsync(H1, h1, szH1 * sizeof(float), hipMemcpyDeviceToDevice, stream);
    hipMemcpyAsync(H2, h2, szH2 * sizeof(float), hipMemcpyDeviceToDevice, stream);

    dim3 blk(256);
    for (int it = 0; it < N_ITER; ++it) {
        // E1 = X - H1@M1  [4096,2048], K=1024
        gemm_ep<1><<<dim3(2048 / 64, 4096 / 64), blk, 0, stream>>>(H1, M1, E, X, nullptr, nullptr,
                                                                   4096, 2048, 1024);
        // P2 = H2@M2  [4096,1024], K=512
        gemm_ep<0><<<dim3(1024 / 64, 4096 / 64), blk, 0, stream>>>(H2, M2, P2, nullptr, nullptr,
                                                                   nullptr, 4096, 1024, 512);
        // H1 -= ALPHA*clip(-(E1@M1r) + H1 - P2)  [4096,1024], K=2048
        gemm_ep<2><<<dim3(1024 / 64, 4096 / 64), blk, 0, stream>>>(E, M1r, nullptr, H1, P2, H1,
                                                                   4096, 1024, 2048);
        // E2 = H1 - P2  [4096,1024]
        sub_kernel<<<(int)((szH1 / 4 + 255) / 256), blk, 0, stream>>>(H1, P2, E, (int)(szH1 / 4));
        // H2 -= ALPHA*clip(-(E2@M2r))  [4096,512], K=1024
        gemm_ep<3><<<dim3(512 / 64, 4096 / 64), blk, 0, stream>>>(E, M2r, nullptr, H2, nullptr, H2,
                                                                  4096, 512, 1024);
    }

    // x passes through unchanged; written last since its region doubled as E scratch
    hipMemcpyAsync(outX, X, szX * sizeof(float), hipMemcpyDeviceToDevice, stream);
}

// Round 2
// 2727.635 us; speedup vs baseline: 4.6047x; 4.6047x over previous
//
#include <hip/hip_runtime.h>

#define N_ITER 20
#define ALPHA 0.01f

typedef unsigned short ushort_t;
typedef __attribute__((ext_vector_type(8))) short bf16x8;
typedef __attribute__((ext_vector_type(4))) float f32x4;

__device__ __forceinline__ float csign(int a, int b) {
    int s = 0;
    for (int aa = a >> 1; aa; aa >>= 1) s += __popc(aa & b);
    return (s & 1) ? -1.0f : 1.0f;
}

__device__ __forceinline__ float revsign(int b) {
    int k = __popc(b);
    return ((k * (k - 1) / 2) & 1) ? -1.0f : 1.0f;
}

__device__ __forceinline__ ushort_t f2bf(float f) {
    union { float f; unsigned u; } v;
    v.f = f;
    unsigned r = v.u + 0x7fffu + ((v.u >> 16) & 1u);  // RNE; inputs finite
    return (ushort_t)(r >> 16);
}

__device__ __forceinline__ void async16(const void* g, void* l) {
    __builtin_amdgcn_global_load_lds((const __attribute__((address_space(1))) void*)g,
                                     (__attribute__((address_space(3))) void*)l, 16, 0, 0);
}

// Build bf16 B^T ("[N][K]") GP matrices from W [P, Q, 8]:
//  forward  Mf[k=(q*8+a)][n=(p*8+c)] = sign(a,a^c)*W[p,q,a^c]          -> Mfbt [P*8][Q*8]
//  reverse  Mr[k=(p*8+a)][n=(q*8+c)] = sign(a,a^c)*REV[a^c]*W[p,q,a^c] -> Mrbt [Q*8][P*8]
__global__ void build_M_kernel(const float* __restrict__ W, ushort_t* __restrict__ Mfbt,
                               ushort_t* __restrict__ Mrbt, int P, int Q) {
    int idx = blockIdx.x * blockDim.x + threadIdx.x;
    int total = P * Q * 64;
    if (idx >= total) return;
    int c = idx & 7;
    int a = (idx >> 3) & 7;
    int pq = idx >> 6;
    int q = pq % Q;
    int p = pq / Q;
    int b = a ^ c;
    float w = W[((size_t)p * Q + q) * 8 + b];
    float s = csign(a, b);
    Mfbt[(size_t)(p * 8 + c) * (Q * 8) + (q * 8 + a)] = f2bf(s * w);
    Mrbt[(size_t)(q * 8 + c) * (P * 8) + (p * 8 + a)] = f2bf(s * revsign(b) * w);
}

__global__ void f2bf_kernel(const float* __restrict__ in, ushort_t* __restrict__ out, int n) {
    int i = blockIdx.x * blockDim.x + threadIdx.x;
    if (i < n) out[i] = f2bf(in[i]);
}

// MFMA bf16 GEMM, 128x128 tile, BK=32, 256 threads (4 waves, 2x2), 4x4 MFMA per wave.
// A [4096, K] bf16, BT [N, K] bf16. M fixed 4096 via grid.
// MODE 0: C fp32 = A@B
// MODE 1: Bout bf16 = bf16(X - A@B)                      (E1 = X - pred)
// MODE 2: h=X; p=P; g=clip(-acc+h-p); hn=h-ALPHA*g; Hout=hn; Bout=bf16(hn); B2out=bf16(hn-p)
// MODE 3: h=X; g=clip(-acc);          hn=h-ALPHA*g; Hout=hn; Bout=bf16(hn)
template <int MODE>
__global__ __launch_bounds__(256) void mfma_gemm(const ushort_t* __restrict__ A,
                                                 const ushort_t* __restrict__ BT,
                                                 float* __restrict__ C,
                                                 const float* __restrict__ X,
                                                 const float* __restrict__ P,
                                                 float* __restrict__ Hout,
                                                 ushort_t* __restrict__ Bout,
                                                 ushort_t* __restrict__ B2out,
                                                 int K, int N) {
    __shared__ ushort_t As[128 * 32];
    __shared__ ushort_t Bs[128 * 32];

    const int t = threadIdx.x;
    const int lane = t & 63;
    const int w = t >> 6;        // wave 0..3
    const int wr = w >> 1;       // wave row (0..1)
    const int wc = w & 1;        // wave col (0..1)
    const int lm = lane & 15;    // m/n index within a 16x16 tile
    const int quad = lane >> 4;  // 0..3
    const int row0 = blockIdx.y * 128;
    const int col0 = blockIdx.x * 128;

    // staging: 8 chunks of 1024B per tile; wave w stages chunks 2w, 2w+1.
    // chunk = 16 rows x 32 k of bf16; lane i -> row i/4, k-off (i%4)*8
    const int srow = lane >> 2;
    const int skoff = (lane & 3) * 8;

    f32x4 acc[4][4];
#pragma unroll
    for (int i = 0; i < 4; ++i)
#pragma unroll
        for (int j = 0; j < 4; ++j) acc[i][j] = (f32x4){0.f, 0.f, 0.f, 0.f};

    for (int k0 = 0; k0 < K; k0 += 32) {
#pragma unroll
        for (int c = 0; c < 2; ++c) {
            int ch = w * 2 + c;
            async16(A + (size_t)(row0 + ch * 16 + srow) * K + (k0 + skoff), &As[ch * 512]);
            async16(BT + (size_t)(col0 + ch * 16 + srow) * K + (k0 + skoff), &Bs[ch * 512]);
        }
        __syncthreads();
        bf16x8 af[4], bfr[4];
#pragma unroll
        for (int i = 0; i < 4; ++i)
            af[i] = *(const bf16x8*)&As[(wr * 64 + i * 16 + lm) * 32 + quad * 8];
#pragma unroll
        for (int j = 0; j < 4; ++j)
            bfr[j] = *(const bf16x8*)&Bs[(wc * 64 + j * 16 + lm) * 32 + quad * 8];
#pragma unroll
        for (int i = 0; i < 4; ++i)
#pragma unroll
            for (int j = 0; j < 4; ++j)
                acc[i][j] = __builtin_amdgcn_mfma_f32_16x16x32_bf16(af[i], bfr[j], acc[i][j], 0, 0, 0);
        __syncthreads();
    }

    // epilogue: C/D layout col=lane&15, row=quad*4+reg
#pragma unroll
    for (int i = 0; i < 4; ++i) {
#pragma unroll
        for (int r = 0; r < 4; ++r) {
            int row = row0 + wr * 64 + i * 16 + quad * 4 + r;
            size_t base = (size_t)row * N + col0 + wc * 64 + lm;
#pragma unroll
            for (int j = 0; j < 4; ++j) {
                size_t off = base + (size_t)j * 16;
                float v = acc[i][j][r];
                if (MODE == 0) {
                    C[off] = v;
                } else if (MODE == 1) {
                    Bout[off] = f2bf(X[off] - v);
                } else if (MODE == 2) {
                    float h = X[off];
                    float p = P[off];
                    float g = fminf(fmaxf(-v + h - p, -1.0f), 1.0f);
                    float hn = h - ALPHA * g;
                    Hout[off] = hn;
                    Bout[off] = f2bf(hn);
                    B2out[off] = f2bf(hn - p);
                } else {  // MODE 3
                    float h = X[off];
                    float g = fminf(fmaxf(-v, -1.0f), 1.0f);
                    float hn = h - ALPHA * g;
                    Hout[off] = hn;
                    Bout[off] = f2bf(hn);
                }
            }
        }
    }
}

extern "C" void kernel_launch(void* const* d_in, const int* in_sizes, int n_in,
                              void* d_out, int out_size, void* d_ws, size_t ws_size,
                              hipStream_t stream) {
    const float* X  = (const float*)d_in[0];  // [4096, 256, 8]
    const float* W1 = (const float*)d_in[1];  // [256, 128, 8]
    const float* W2 = (const float*)d_in[2];  // [128, 64, 8]
    const float* h1 = (const float*)d_in[3];  // [4096, 128, 8]
    const float* h2 = (const float*)d_in[4];  // [4096, 64, 8]
    float* out = (float*)d_out;

    const size_t szX  = (size_t)4096 * 2048;  // 8388608
    const size_t szH1 = (size_t)4096 * 1024;  // 4194304
    const size_t szH2 = (size_t)4096 * 512;   // 2097152

    float* outX = out;
    float* H1 = out + szX;
    float* H2 = H1 + szH1;

    // E buffers (bf16) live in the x output region (32 MB); x copied in at the end.
    ushort_t* E1b = (ushort_t*)outX;                 // [4096, 2048] bf16 = 16 MB
    ushort_t* E2b = (ushort_t*)(outX + szX / 2);     // [4096, 1024] bf16 = 8 MB

    // workspace: 4+4+1+1+16+8+4 = 38 MB
    ushort_t* M1bt  = (ushort_t*)d_ws;               // [2048, 1024] bf16
    ushort_t* M1rbt = M1bt + (size_t)2048 * 1024;    // [1024, 2048] bf16
    ushort_t* M2bt  = M1rbt + (size_t)1024 * 2048;   // [1024, 512]  bf16
    ushort_t* M2rbt = M2bt + (size_t)1024 * 512;     // [512, 1024]  bf16
    float*    P2    = (float*)(M2rbt + (size_t)512 * 1024);  // [4096, 1024] fp32
    ushort_t* H1b   = (ushort_t*)(P2 + szH1);        // [4096, 1024] bf16
    ushort_t* H2b   = H1b + szH1;                    // [4096, 512]  bf16

    build_M_kernel<<<(256 * 128 * 64 + 255) / 256, 256, 0, stream>>>(W1, M1bt, M1rbt, 256, 128);
    build_M_kernel<<<(128 * 64 * 64 + 255) / 256, 256, 0, stream>>>(W2, M2bt, M2rbt, 128, 64);

    hipMemcpyAsync(H1, h1, szH1 * sizeof(float), hipMemcpyDeviceToDevice, stream);
    hipMemcpyAsync(H2, h2, szH2 * sizeof(float), hipMemcpyDeviceToDevice, stream);
    f2bf_kernel<<<(int)((szH1 + 255) / 256), 256, 0, stream>>>(h1, H1b, (int)szH1);
    f2bf_kernel<<<(int)((szH2 + 255) / 256), 256, 0, stream>>>(h2, H2b, (int)szH2);

    for (int it = 0; it < N_ITER; ++it) {
        // E1b = bf16(X - H1@M1)   [4096,2048], K=1024
        mfma_gemm<1><<<dim3(2048 / 128, 4096 / 128), 256, 0, stream>>>(
            H1b, M1bt, nullptr, X, nullptr, nullptr, E1b, nullptr, 1024, 2048);
        // P2 = H2@M2              [4096,1024], K=512
        mfma_gemm<0><<<dim3(1024 / 128, 4096 / 128), 256, 0, stream>>>(
            H2b, M2bt, P2, nullptr, nullptr, nullptr, nullptr, nullptr, 512, 1024);
        // H1 update (+ H1b, E2b)  [4096,1024], K=2048
        mfma_gemm<2><<<dim3(1024 / 128, 4096 / 128), 256, 0, stream>>>(
            E1b, M1rbt, nullptr, H1, P2, H1, H1b, E2b, 2048, 1024);
        // H2 update (+ H2b)       [4096,512],  K=1024
        mfma_gemm<3><<<dim3(512 / 128, 4096 / 128), 256, 0, stream>>>(
            E2b, M2rbt, nullptr, H2, nullptr, H2, H2b, nullptr, 1024, 512);
    }

    // x passes through unchanged; written last since its region held E1b/E2b
    hipMemcpyAsync(outX, X, szX * sizeof(float), hipMemcpyDeviceToDevice, stream);
}

// Round 3
// 2228.058 us; speedup vs baseline: 5.6372x; 1.2242x over previous
//
#include <hip/hip_runtime.h>

#define N_ITER 20
#define ALPHA 0.01f

typedef unsigned short ushort_t;
typedef __attribute__((ext_vector_type(8))) short bf16x8;
typedef __attribute__((ext_vector_type(4))) float f32x4;

__device__ __forceinline__ float csign(int a, int b) {
    int s = 0;
    for (int aa = a >> 1; aa; aa >>= 1) s += __popc(aa & b);
    return (s & 1) ? -1.0f : 1.0f;
}

__device__ __forceinline__ float revsign(int b) {
    int k = __popc(b);
    return ((k * (k - 1) / 2) & 1) ? -1.0f : 1.0f;
}

__device__ __forceinline__ ushort_t f2bf(float f) {
    union { float f; unsigned u; } v;
    v.f = f;
    unsigned r = v.u + 0x7fffu + ((v.u >> 16) & 1u);  // RNE; inputs finite
    return (ushort_t)(r >> 16);
}

__device__ __forceinline__ void async16(const void* g, void* l) {
    __builtin_amdgcn_global_load_lds((const __attribute__((address_space(1))) void*)g,
                                     (__attribute__((address_space(3))) void*)l, 16, 0, 0);
}

// Build bf16 B^T ("[N][K]") GP matrices from W [P, Q, 8]:
//  forward  Mf[k=(q*8+a)][n=(p*8+c)] = sign(a,a^c)*W[p,q,a^c]          -> Mfbt [P*8][Q*8]
//  reverse  Mr[k=(p*8+a)][n=(q*8+c)] = sign(a,a^c)*REV[a^c]*W[p,q,a^c] -> Mrbt [Q*8][P*8]
__global__ void build_M_kernel(const float* __restrict__ W, ushort_t* __restrict__ Mfbt,
                               ushort_t* __restrict__ Mrbt, int P, int Q) {
    int idx = blockIdx.x * blockDim.x + threadIdx.x;
    int total = P * Q * 64;
    if (idx >= total) return;
    int c = idx & 7;
    int a = (idx >> 3) & 7;
    int pq = idx >> 6;
    int q = pq % Q;
    int p = pq / Q;
    int b = a ^ c;
    float w = W[((size_t)p * Q + q) * 8 + b];
    float s = csign(a, b);
    Mfbt[(size_t)(p * 8 + c) * (Q * 8) + (q * 8 + a)] = f2bf(s * w);
    Mrbt[(size_t)(q * 8 + c) * (P * 8) + (p * 8 + a)] = f2bf(s * revsign(b) * w);
}

__global__ void f2bf_kernel(const float* __restrict__ in, ushort_t* __restrict__ out, int n) {
    int i = blockIdx.x * blockDim.x + threadIdx.x;
    if (i < n) out[i] = f2bf(in[i]);
}

// MFMA bf16 GEMM, BMxBN tile, BK=32, 256 threads (4 waves, 2x2), each wave (BM/2)x(BN/2).
// A [M, K] bf16, BT [N, K] bf16.
// MODE 0: C fp32 = A@B
// MODE 1: Bout bf16 = bf16(X - A@B)
// MODE 2: h=X; p=P; g=clip(-acc+h-p); hn=h-ALPHA*g; Hout=hn; Bout=bf16(hn); B2out=bf16(hn-p)
// MODE 3: h=X; g=clip(-acc);          hn=h-ALPHA*g; Hout=hn; Bout=bf16(hn)
template <int MODE, int BM, int BN>
__global__ __launch_bounds__(256) void mfma_gemm(const ushort_t* __restrict__ A,
                                                 const ushort_t* __restrict__ BT,
                                                 float* __restrict__ C,
                                                 const float* __restrict__ X,
                                                 const float* __restrict__ P,
                                                 float* __restrict__ Hout,
                                                 ushort_t* __restrict__ Bout,
                                                 ushort_t* __restrict__ B2out,
                                                 int K, int N) {
    constexpr int MI = BM / 32;          // 16-row tiles per wave (M dir)
    constexpr int NJ = BN / 32;          // 16-col tiles per wave (N dir)
    constexpr int NCH = (BM + BN) / 16;  // 1KB staging chunks per K-step
    constexpr int CPW = NCH / 4;         // chunks per wave
    __shared__ ushort_t S[(BM + BN) * 32];  // A tile then B tile, [row][32k]

    const int t = threadIdx.x;
    const int lane = t & 63;
    const int w = t >> 6;
    const int wr = w >> 1;
    const int wc = w & 1;
    const int lm = lane & 15;
    const int quad = lane >> 4;
    const int row0 = blockIdx.y * BM;
    const int col0 = blockIdx.x * BN;

    const int srow = lane >> 2;        // chunk: 16 rows x 32 k; lane -> row l/4, k (l%4)*8
    const int skoff = (lane & 3) * 8;

    // per-wave staging pointers (wave-uniform LDS dst, global src advances by 32 elems)
    const ushort_t* gp[CPW];
    int lofs[CPW];
#pragma unroll
    for (int cc = 0; cc < CPW; ++cc) {
        int ch = cc * 4 + w;
        if (ch < BM / 16) {
            gp[cc] = A + (size_t)(row0 + ch * 16 + srow) * K + skoff;
        } else {
            gp[cc] = BT + (size_t)(col0 + (ch - BM / 16) * 16 + srow) * K + skoff;
        }
        lofs[cc] = ch * 512;
    }

    f32x4 acc[MI][NJ];
#pragma unroll
    for (int i = 0; i < MI; ++i)
#pragma unroll
        for (int j = 0; j < NJ; ++j) acc[i][j] = (f32x4){0.f, 0.f, 0.f, 0.f};

    for (int k0 = 0; k0 < K; k0 += 32) {
#pragma unroll
        for (int cc = 0; cc < CPW; ++cc) {
            async16(gp[cc], &S[lofs[cc]]);
            gp[cc] += 32;
        }
        __syncthreads();
        bf16x8 af[MI], bfr[NJ];
#pragma unroll
        for (int i = 0; i < MI; ++i)
            af[i] = *(const bf16x8*)&S[(wr * (BM / 2) + i * 16 + lm) * 32 + quad * 8];
#pragma unroll
        for (int j = 0; j < NJ; ++j)
            bfr[j] = *(const bf16x8*)&S[BM * 32 + (wc * (BN / 2) + j * 16 + lm) * 32 + quad * 8];
#pragma unroll
        for (int i = 0; i < MI; ++i)
#pragma unroll
            for (int j = 0; j < NJ; ++j)
                acc[i][j] = __builtin_amdgcn_mfma_f32_16x16x32_bf16(af[i], bfr[j], acc[i][j], 0, 0, 0);
        __syncthreads();
    }

    // epilogue: C/D layout col=lane&15, row=quad*4+reg
#pragma unroll
    for (int i = 0; i < MI; ++i) {
#pragma unroll
        for (int r = 0; r < 4; ++r) {
            int row = row0 + wr * (BM / 2) + i * 16 + quad * 4 + r;
            size_t base = (size_t)row * N + col0 + wc * (BN / 2) + lm;
#pragma unroll
            for (int j = 0; j < NJ; ++j) {
                size_t off = base + (size_t)j * 16;
                float v = acc[i][j][r];
                if (MODE == 0) {
                    C[off] = v;
                } else if (MODE == 1) {
                    Bout[off] = f2bf(X[off] - v);
                } else if (MODE == 2) {
                    float h = X[off];
                    float p = P[off];
                    float g = fminf(fmaxf(-v + h - p, -1.0f), 1.0f);
                    float hn = h - ALPHA * g;
                    Hout[off] = hn;
                    Bout[off] = f2bf(hn);
                    B2out[off] = f2bf(hn - p);
                } else {  // MODE 3
                    float h = X[off];
                    float g = fminf(fmaxf(-v, -1.0f), 1.0f);
                    float hn = h - ALPHA * g;
                    Hout[off] = hn;
                    Bout[off] = f2bf(hn);
                }
            }
        }
    }
}

extern "C" void kernel_launch(void* const* d_in, const int* in_sizes, int n_in,
                              void* d_out, int out_size, void* d_ws, size_t ws_size,
                              hipStream_t stream) {
    const float* X  = (const float*)d_in[0];  // [4096, 256, 8]
    const float* W1 = (const float*)d_in[1];  // [256, 128, 8]
    const float* W2 = (const float*)d_in[2];  // [128, 64, 8]
    const float* h1 = (const float*)d_in[3];  // [4096, 128, 8]
    const float* h2 = (const float*)d_in[4];  // [4096, 64, 8]
    float* out = (float*)d_out;

    const size_t szX  = (size_t)4096 * 2048;  // 8388608
    const size_t szH1 = (size_t)4096 * 1024;  // 4194304
    const size_t szH2 = (size_t)4096 * 512;   // 2097152

    float* outX = out;
    float* H1 = out + szX;
    float* H2 = H1 + szH1;

    // E buffers (bf16) live in the x output region (32 MB); x copied in at the end.
    ushort_t* E1b = (ushort_t*)outX;              // [4096, 2048] bf16 = 16 MB
    ushort_t* E2b = (ushort_t*)(outX + szX / 2);  // [4096, 1024] bf16 = 8 MB

    ushort_t* M1bt  = (ushort_t*)d_ws;             // [2048, 1024] bf16
    ushort_t* M1rbt = M1bt + (size_t)2048 * 1024;  // [1024, 2048] bf16
    ushort_t* M2bt  = M1rbt + (size_t)1024 * 2048; // [1024, 512]  bf16
    ushort_t* M2rbt = M2bt + (size_t)1024 * 512;   // [512, 1024]  bf16
    float*    P2    = (float*)(M2rbt + (size_t)512 * 1024);  // [4096, 1024] fp32
    ushort_t* H1b   = (ushort_t*)(P2 + szH1);      // [4096, 1024] bf16
    ushort_t* H2b   = H1b + szH1;                  // [4096, 512]  bf16

    build_M_kernel<<<(256 * 128 * 64 + 255) / 256, 256, 0, stream>>>(W1, M1bt, M1rbt, 256, 128);
    build_M_kernel<<<(128 * 64 * 64 + 255) / 256, 256, 0, stream>>>(W2, M2bt, M2rbt, 128, 64);

    hipMemcpyAsync(H1, h1, szH1 * sizeof(float), hipMemcpyDeviceToDevice, stream);
    hipMemcpyAsync(H2, h2, szH2 * sizeof(float), hipMemcpyDeviceToDevice, stream);
    f2bf_kernel<<<(int)((szH1 + 255) / 256), 256, 0, stream>>>(h1, H1b, (int)szH1);
    f2bf_kernel<<<(int)((szH2 + 255) / 256), 256, 0, stream>>>(h2, H2b, (int)szH2);

    for (int it = 0; it < N_ITER; ++it) {
        // E1b = bf16(X - H1@M1)   [4096,2048], K=1024 -> 16x64 = 1024 blocks
        mfma_gemm<1, 64, 128><<<dim3(2048 / 128, 4096 / 64), 256, 0, stream>>>(
            H1b, M1bt, nullptr, X, nullptr, nullptr, E1b, nullptr, 1024, 2048);
        // P2 = H2@M2              [4096,1024], K=512 -> 16x64 = 1024 blocks
        mfma_gemm<0, 64, 64><<<dim3(1024 / 64, 4096 / 64), 256, 0, stream>>>(
            H2b, M2bt, P2, nullptr, nullptr, nullptr, nullptr, nullptr, 512, 1024);
        // H1 update (+ H1b, E2b)  [4096,1024], K=2048 -> 16x64 = 1024 blocks
        mfma_gemm<2, 64, 64><<<dim3(1024 / 64, 4096 / 64), 256, 0, stream>>>(
            E1b, M1rbt, nullptr, H1, P2, H1, H1b, E2b, 2048, 1024);
        // H2 update (+ H2b)       [4096,512],  K=1024 -> 8x64 = 512 blocks
        mfma_gemm<3, 64, 64><<<dim3(512 / 64, 4096 / 64), 256, 0, stream>>>(
            E2b, M2rbt, nullptr, H2, nullptr, H2, H2b, nullptr, 1024, 512);
    }

    // x passes through unchanged; written last since its region held E1b/E2b
    hipMemcpyAsync(outX, X, szX * sizeof(float), hipMemcpyDeviceToDevice, stream);
}

// Round 4
// 1840.039 us; speedup vs baseline: 6.8259x; 1.2109x over previous
//
#include <hip/hip_runtime.h>

#define N_ITER 20
#define ALPHA 0.01f

typedef unsigned short ushort_t;
typedef __attribute__((ext_vector_type(8))) short bf16x8;
typedef __attribute__((ext_vector_type(4))) float f32x4;

__device__ __forceinline__ float csign(int a, int b) {
    int s = 0;
    for (int aa = a >> 1; aa; aa >>= 1) s += __popc(aa & b);
    return (s & 1) ? -1.0f : 1.0f;
}

__device__ __forceinline__ float revsign(int b) {
    int k = __popc(b);
    return ((k * (k - 1) / 2) & 1) ? -1.0f : 1.0f;
}

__device__ __forceinline__ ushort_t f2bf(float f) {
    union { float f; unsigned u; } v;
    v.f = f;
    unsigned r = v.u + 0x7fffu + ((v.u >> 16) & 1u);  // RNE; inputs finite
    return (ushort_t)(r >> 16);
}

__device__ __forceinline__ float bf2f(ushort_t u) {
    union { unsigned u; float f; } v;
    v.u = ((unsigned)u) << 16;
    return v.f;
}

// Swizzled storage index for logical (r, k) in an [R][K] bf16 GEMM-operand buffer.
// 16B block j of row r lives at block (j ^ (r&7)) within each 64-element k-group,
// so LDS staging is a verbatim row copy and ds_read_b128 frag reads are conflict-free.
__device__ __forceinline__ size_t swz(int r, int k, int K) {
    return (size_t)r * K + (k & ~63) + ((((k >> 3) ^ r) & 7) << 3) + (k & 7);
}

__device__ __forceinline__ void async16(const void* g, void* l) {
    __builtin_amdgcn_global_load_lds((const __attribute__((address_space(1))) void*)g,
                                     (__attribute__((address_space(3))) void*)l, 16, 0, 0);
}

// Build bf16 swizzled B^T ("[N][K]") GP matrices from W [P, Q, 8]:
//  forward  Mf[k=(q*8+a)][n=(p*8+c)] = sign(a,a^c)*W[p,q,a^c]          -> Mfbt [P*8][Q*8]
//  reverse  Mr[k=(p*8+a)][n=(q*8+c)] = sign(a,a^c)*REV[a^c]*W[p,q,a^c] -> Mrbt [Q*8][P*8]
__global__ void build_M_kernel(const float* __restrict__ W, ushort_t* __restrict__ Mfbt,
                               ushort_t* __restrict__ Mrbt, int P, int Q) {
    int idx = blockIdx.x * blockDim.x + threadIdx.x;
    int total = P * Q * 64;
    if (idx >= total) return;
    int c = idx & 7;
    int a = (idx >> 3) & 7;
    int pq = idx >> 6;
    int q = pq % Q;
    int p = pq / Q;
    int b = a ^ c;
    float w = W[((size_t)p * Q + q) * 8 + b];
    float s = csign(a, b);
    Mfbt[swz(p * 8 + c, q * 8 + a, Q * 8)] = f2bf(s * w);
    Mrbt[swz(q * 8 + c, p * 8 + a, P * 8)] = f2bf(s * revsign(b) * w);
}

// fp32 [R][K] plain -> bf16 swizzled
__global__ void f2bf_swz_kernel(const float* __restrict__ in, ushort_t* __restrict__ out,
                                int n, int kshift) {
    int i = blockIdx.x * blockDim.x + threadIdx.x;
    if (i >= n) return;
    int K = 1 << kshift;
    int r = i >> kshift;
    int k = i & (K - 1);
    out[swz(r, k, K)] = f2bf(in[i]);
}

// MFMA bf16 GEMM, 64x64 block, BK=64 double-buffered, 256 threads (4 waves, 2x2),
// wave tile 32x32 (MI=NJ=2). A [M,K] bf16 swizzled, BT [N,K] bf16 swizzled.
// MODE 0: Bout bf16 plain = bf16(A@B)                                (P2b)
// MODE 1: Bout bf16 swz   = bf16(X - A@B)                            (E1b)
// MODE 2: h=X; p=Pb; g=clip(-acc+h-p); hn=h-a*g; Hout=hn; Bout=swz(hn); B2out=swz(hn-p)
// MODE 3: h=X; g=clip(-acc);           hn=h-a*g; Hout=hn; Bout=swz(hn)
template <int MODE>
__global__ __launch_bounds__(256) void mfma_gemm(const ushort_t* __restrict__ A,
                                                 const ushort_t* __restrict__ BT,
                                                 const float* __restrict__ X,
                                                 const ushort_t* __restrict__ Pb,
                                                 float* __restrict__ Hout,
                                                 ushort_t* __restrict__ Bout,
                                                 ushort_t* __restrict__ B2out,
                                                 int K, int N) {
    constexpr int SBUF = 128 * 64;  // elements per LDS buffer (A 64 rows + B 64 rows, 64 k)
    __shared__ ushort_t S[2][SBUF];

    const int t = threadIdx.x;
    const int lane = t & 63;
    const int w = t >> 6;
    const int wr = w >> 1;
    const int wc = w & 1;
    const int lm = lane & 15;
    const int quad = lane >> 4;
    const int row0 = blockIdx.y * 64;
    const int col0 = blockIdx.x * 64;

    // staging: 16 chunks of 1KB (8 rows x 64k bf16); wave w stages chunks w, w+4, w+8, w+12
    const int srow = lane >> 3;
    const int skoff = (lane & 7) * 8;
    const ushort_t* gp[4];
    int lofs[4];
#pragma unroll
    for (int cc = 0; cc < 4; ++cc) {
        int ch = cc * 4 + w;
        if (ch < 8) {
            gp[cc] = A + (size_t)(row0 + ch * 8 + srow) * K + skoff;
        } else {
            gp[cc] = BT + (size_t)(col0 + (ch - 8) * 8 + srow) * K + skoff;
        }
        lofs[cc] = ch * 512;
    }

    f32x4 acc[2][2];
#pragma unroll
    for (int i = 0; i < 2; ++i)
#pragma unroll
        for (int j = 0; j < 2; ++j) acc[i][j] = (f32x4){0.f, 0.f, 0.f, 0.f};

    const int T = K >> 6;
    // prologue: stage tile 0 into S[0]
#pragma unroll
    for (int cc = 0; cc < 4; ++cc) {
        async16(gp[cc], &S[0][lofs[cc]]);
        gp[cc] += 64;
    }
    __syncthreads();

    const int sw = lm & 7;  // row-dependent swizzle selector (lr&7 == lm&7 here)
    for (int tt = 0; tt < T; ++tt) {
        const ushort_t* cur = S[tt & 1];
        bf16x8 af[2][2], bfm[2][2];
#pragma unroll
        for (int h = 0; h < 2; ++h) {
#pragma unroll
            for (int i = 0; i < 2; ++i)
                af[h][i] = *(const bf16x8*)&cur[(wr * 32 + i * 16 + lm) * 64 +
                                                (((h * 4 + quad) ^ sw) << 3)];
#pragma unroll
            for (int j = 0; j < 2; ++j)
                bfm[h][j] = *(const bf16x8*)&cur[64 * 64 + (wc * 32 + j * 16 + lm) * 64 +
                                                 (((h * 4 + quad) ^ sw) << 3)];
        }
        if (tt + 1 < T) {
            ushort_t* nxt = S[(tt + 1) & 1];
#pragma unroll
            for (int cc = 0; cc < 4; ++cc) {
                async16(gp[cc], &nxt[lofs[cc]]);
                gp[cc] += 64;
            }
        }
#pragma unroll
        for (int h = 0; h < 2; ++h)
#pragma unroll
            for (int i = 0; i < 2; ++i)
#pragma unroll
                for (int j = 0; j < 2; ++j)
                    acc[i][j] = __builtin_amdgcn_mfma_f32_16x16x32_bf16(af[h][i], bfm[h][j],
                                                                        acc[i][j], 0, 0, 0);
        __syncthreads();
    }

    // epilogue: C/D layout col=lane&15, row=quad*4+reg
#pragma unroll
    for (int i = 0; i < 2; ++i) {
#pragma unroll
        for (int r = 0; r < 4; ++r) {
            int row = row0 + wr * 32 + i * 16 + quad * 4 + r;
#pragma unroll
            for (int j = 0; j < 2; ++j) {
                int col = col0 + wc * 32 + j * 16 + lm;
                size_t off = (size_t)row * N + col;
                float v = acc[i][j][r];
                if (MODE == 0) {
                    Bout[off] = f2bf(v);
                } else if (MODE == 1) {
                    Bout[swz(row, col, N)] = f2bf(X[off] - v);
                } else if (MODE == 2) {
                    float h = X[off];
                    float p = bf2f(Pb[off]);
                    float g = fminf(fmaxf(-v + h - p, -1.0f), 1.0f);
                    float hn = h - ALPHA * g;
                    Hout[off] = hn;
                    size_t so = swz(row, col, N);
                    Bout[so] = f2bf(hn);
                    B2out[so] = f2bf(hn - p);
                } else {  // MODE 3
                    float h = X[off];
                    float g = fminf(fmaxf(-v, -1.0f), 1.0f);
                    float hn = h - ALPHA * g;
                    Hout[off] = hn;
                    Bout[swz(row, col, N)] = f2bf(hn);
                }
            }
        }
    }
}

extern "C" void kernel_launch(void* const* d_in, const int* in_sizes, int n_in,
                              void* d_out, int out_size, void* d_ws, size_t ws_size,
                              hipStream_t stream) {
    const float* X  = (const float*)d_in[0];  // [4096, 256, 8]
    const float* W1 = (const float*)d_in[1];  // [256, 128, 8]
    const float* W2 = (const float*)d_in[2];  // [128, 64, 8]
    const float* h1 = (const float*)d_in[3];  // [4096, 128, 8]
    const float* h2 = (const float*)d_in[4];  // [4096, 64, 8]
    float* out = (float*)d_out;

    const size_t szX  = (size_t)4096 * 2048;
    const size_t szH1 = (size_t)4096 * 1024;
    const size_t szH2 = (size_t)4096 * 512;

    float* outX = out;
    float* H1 = out + szX;
    float* H2 = H1 + szH1;

    // E buffers (bf16, swizzled) live in the x output region; x copied in at the end.
    ushort_t* E1b = (ushort_t*)outX;              // [4096, 2048] bf16 = 16 MB
    ushort_t* E2b = (ushort_t*)(outX + szX / 2);  // [4096, 1024] bf16 = 8 MB

    // workspace: 4+4+1+1+8+8+4 = 30 MB
    ushort_t* M1bt  = (ushort_t*)d_ws;             // [2048, 1024] swz
    ushort_t* M1rbt = M1bt + (size_t)2048 * 1024;  // [1024, 2048] swz
    ushort_t* M2bt  = M1rbt + (size_t)1024 * 2048; // [1024, 512]  swz
    ushort_t* M2rbt = M2bt + (size_t)1024 * 512;   // [512, 1024]  swz
    ushort_t* P2b   = M2rbt + (size_t)512 * 1024;  // [4096, 1024] plain bf16
    ushort_t* H1b   = P2b + szH1;                  // [4096, 1024] swz
    ushort_t* H2b   = H1b + szH1;                  // [4096, 512]  swz

    build_M_kernel<<<(256 * 128 * 64 + 255) / 256, 256, 0, stream>>>(W1, M1bt, M1rbt, 256, 128);
    build_M_kernel<<<(128 * 64 * 64 + 255) / 256, 256, 0, stream>>>(W2, M2bt, M2rbt, 128, 64);

    hipMemcpyAsync(H1, h1, szH1 * sizeof(float), hipMemcpyDeviceToDevice, stream);
    hipMemcpyAsync(H2, h2, szH2 * sizeof(float), hipMemcpyDeviceToDevice, stream);
    f2bf_swz_kernel<<<(int)((szH1 + 255) / 256), 256, 0, stream>>>(h1, H1b, (int)szH1, 10);
    f2bf_swz_kernel<<<(int)((szH2 + 255) / 256), 256, 0, stream>>>(h2, H2b, (int)szH2, 9);

    for (int it = 0; it < N_ITER; ++it) {
        // E1b = swz(bf16(X - H1@M1))   [4096,2048], K=1024 -> 32x64 = 2048 blocks
        mfma_gemm<1><<<dim3(2048 / 64, 4096 / 64), 256, 0, stream>>>(
            H1b, M1bt, X, nullptr, nullptr, E1b, nullptr, 1024, 2048);
        // P2b = bf16(H2@M2) plain      [4096,1024], K=512  -> 16x64 = 1024 blocks
        mfma_gemm<0><<<dim3(1024 / 64, 4096 / 64), 256, 0, stream>>>(
            H2b, M2bt, nullptr, nullptr, nullptr, P2b, nullptr, 512, 1024);
        // H1 update (+ H1b, E2b)       [4096,1024], K=2048 -> 16x64 = 1024 blocks
        mfma_gemm<2><<<dim3(1024 / 64, 4096 / 64), 256, 0, stream>>>(
            E1b, M1rbt, H1, P2b, H1, H1b, E2b, 2048, 1024);
        // H2 update (+ H2b)            [4096,512],  K=1024 -> 8x64 = 512 blocks
        mfma_gemm<3><<<dim3(512 / 64, 4096 / 64), 256, 0, stream>>>(
            E2b, M2rbt, H2, nullptr, H2, H2b, nullptr, 1024, 512);
    }

    // x passes through unchanged; written last since its region held E1b/E2b
    hipMemcpyAsync(outX, X, szX * sizeof(float), hipMemcpyDeviceToDevice, stream);
}